// Round 1
// baseline (380.156 us; speedup 1.0000x reference)
//
#include <hip/hip_runtime.h>
#include <hip/hip_bf16.h>

#define T_TOK 4096
#define H_DIM 512
#define I_DIM 1024
#define E_NUM 32
#define KTOP  2
#define CAP   512
#define NROWS (E_NUM * CAP)    // 16384
#define NPAIR (T_TOK * KTOP)   // 8192

typedef __attribute__((ext_vector_type(8))) short short8;    // 8 bf16 = 4 VGPRs
typedef __attribute__((ext_vector_type(4))) float float4v;
typedef __attribute__((ext_vector_type(4))) unsigned int uint4v;

__device__ __forceinline__ unsigned short f2bf_rne(float f) {
  unsigned int u = __float_as_uint(f);
  u += 0x7FFFu + ((u >> 16) & 1u);
  return (unsigned short)(u >> 16);
}
__device__ __forceinline__ unsigned int pack_bf2(float a, float b) {
  return (unsigned int)f2bf_rne(a) | ((unsigned int)f2bf_rne(b) << 16);
}
__device__ __forceinline__ float bf2f(unsigned short s) {
  return __uint_as_float(((unsigned int)s) << 16);
}

#define GLOAD_LDS16(gptr, lptr)                                                         \
  __builtin_amdgcn_global_load_lds((const __attribute__((address_space(1))) unsigned int*)(gptr), \
                                   (__attribute__((address_space(3))) unsigned int*)(lptr), 16, 0, 0)

// XOR swizzle used by the fallback (convert-in-gemm) kernels only.
#define SWZ(kc, n) (((kc) << 7) | ((n) ^ ((kc) << 1)))

// ---------------- routing ----------------
__global__ void k_route(const int* __restrict__ idx, int* __restrict__ counts,
                        int* __restrict__ slot_token, int* __restrict__ inv) {
  int i = blockIdx.x * 256 + threadIdx.x;
  if (i >= NPAIR) return;
  int e = idx[i];
  int p = atomicAdd(counts + e, 1);
  if (p < CAP) {
    slot_token[e * CAP + p] = i >> 1;  // KTOP == 2
    inv[i] = e * CAP + p;
  } else {
    inv[i] = -1;
  }
}

// ---------------- gather tokens -> bf16 dispatch buffer (early-exit padded rows) ----
__global__ void k_gather(const float* __restrict__ hs, const int* __restrict__ counts,
                         const int* __restrict__ slot_token, unsigned short* __restrict__ xd) {
  const int r = blockIdx.x * 4 + (threadIdx.x >> 6);  // one wave per row
  const int lane = threadIdx.x & 63;
  const int e = r >> 9;
  const int p = r & (CAP - 1);
  const int cnt = min(counts[e], CAP);
  if (p >= ((cnt + 127) & ~127)) return;  // beyond last active tile: never read
  uint4v v = {0u, 0u, 0u, 0u};
  if (p < cnt) {
    const int t = slot_token[r];
    const float4v* src = (const float4v*)(hs + (size_t)t * H_DIM);
    float4v f0 = src[lane * 2];
    float4v f1 = src[lane * 2 + 1];
    v.x = pack_bf2(f0.x, f0.y);
    v.y = pack_bf2(f0.z, f0.w);
    v.z = pack_bf2(f1.x, f1.y);
    v.w = pack_bf2(f1.z, f1.w);
  }
  *(uint4v*)(xd + (size_t)r * H_DIM + lane * 8) = v;
}

// ---------------- weight convert: fp32 -> bf16, per-expert contiguous row chunk ----
// For each expert e: dst[e*dst_estride + i] = bf16(src[e*src_estride + i]), i < elems.
__global__ void k_wconv(const float* __restrict__ src, unsigned short* __restrict__ dst,
                        size_t src_estride, size_t dst_estride, int elems) {
  const int e = blockIdx.y;
  const int i = (blockIdx.x * 256 + threadIdx.x) * 8;
  if (i >= elems) return;
  const float4v* s = (const float4v*)(src + (size_t)e * src_estride + i);
  float4v f0 = s[0], f1 = s[1];
  uint4v v;
  v.x = pack_bf2(f0.x, f0.y); v.y = pack_bf2(f0.z, f0.w);
  v.z = pack_bf2(f1.x, f1.y); v.w = pack_bf2(f1.z, f1.w);
  *(uint4v*)(dst + (size_t)e * dst_estride + i) = v;
}

// ---------------- GEMM1 (bf16 weights, gload_lds, depth-2 counted-vmcnt pipeline) ----
// xd[NROWS,H] x wb[e][2*CS,H]^T -> silu(g)*u -> act[NROWS,I] (cols c0base..c0base+CS)
__global__ __launch_bounds__(256, 2) void k_gemm1_bf(
    const unsigned short* __restrict__ xd, const unsigned short* __restrict__ wb,
    const int* __restrict__ counts, unsigned short* __restrict__ act,
    int c0base, int CS) {
  // 3 buffers x (A 8KB | Bg 8KB | Bu 8KB) = 72 KB
  __shared__ unsigned short lds[3 * 12288];

  const int c0loc = blockIdx.x * 128;
  const int r0 = blockIdx.y * 128;
  const int e = r0 >> 9;
  if ((r0 & (CAP - 1)) >= min(counts[e], CAP)) return;  // fully-padded tile

  const int tid = threadIdx.x;
  const int lane = tid & 63;
  const int wid = tid >> 6;
  const int wr = wid >> 1, wc = wid & 1;
  const int ml = lane & 15, kg = lane >> 4;

  // staging geometry: chunk ch = q*256 + wid*64 + lane; kc = ch>>7, row = ch&127
  const int ch = tid;                       // q = 0 chunk id
  const int kc0 = ch >> 7, rr = ch & 127;   // q = 1 is kc0+2, same row

  const unsigned short* a_src = xd + (size_t)(r0 + rr) * H_DIM + kc0 * 8;
  const unsigned short* g_src = wb + (size_t)e * (2 * (size_t)CS * H_DIM) +
                                (size_t)(c0loc + rr) * H_DIM + kc0 * 8;
  const unsigned short* u_src = g_src + (size_t)CS * H_DIM;
  const int dst0 = (wid * 64) * 8;          // DMA adds lane*16B
  const int dst1 = (256 + wid * 64) * 8;

  float4v accg[4][4] = {};
  float4v accu[4][4] = {};

  auto STAGE = [&](unsigned short* lb, int kk) {
    GLOAD_LDS16(a_src + kk,      lb + dst0);
    GLOAD_LDS16(a_src + kk + 16, lb + dst1);
    GLOAD_LDS16(g_src + kk,      lb + 4096 + dst0);
    GLOAD_LDS16(g_src + kk + 16, lb + 4096 + dst1);
    GLOAD_LDS16(u_src + kk,      lb + 8192 + dst0);
    GLOAD_LDS16(u_src + kk + 16, lb + 8192 + dst1);
  };
  auto COMPUTE = [&](const unsigned short* lb) {
    short8 af[4], bgf[4], buf_[4];
#pragma unroll
    for (int mi = 0; mi < 4; ++mi)
      af[mi] = *(const short8*)(lb + (size_t)(kg * 128 + wr * 64 + mi * 16 + ml) * 8);
#pragma unroll
    for (int ni = 0; ni < 4; ++ni) {
      const int o = (kg * 128 + wc * 64 + ni * 16 + ml) * 8;
      bgf[ni] = *(const short8*)(lb + 4096 + o);
      buf_[ni] = *(const short8*)(lb + 8192 + o);
    }
#pragma unroll
    for (int mi = 0; mi < 4; ++mi)
#pragma unroll
      for (int ni = 0; ni < 4; ++ni) {
        accg[mi][ni] = __builtin_amdgcn_mfma_f32_16x16x32_bf16(af[mi], bgf[ni], accg[mi][ni], 0, 0, 0);
        accu[mi][ni] = __builtin_amdgcn_mfma_f32_16x16x32_bf16(af[mi], buf_[ni], accu[mi][ni], 0, 0, 0);
      }
  };

  unsigned short* b0 = lds;
  unsigned short* b1 = lds + 12288;
  unsigned short* b2 = lds + 24576;
  STAGE(b0, 0);
  STAGE(b1, 32);
#pragma unroll 1
  for (int t = 0; t < 14; ++t) {            // NT = H/32 = 16; main body covers t=0..13
    asm volatile("s_waitcnt vmcnt(6)" ::: "memory");  // tile t landed; t+1 stays in flight
    __builtin_amdgcn_s_barrier();
    __builtin_amdgcn_sched_barrier(0);
    STAGE(b2, (t + 2) * 32);                // overwrites buffer last read at t-1 (safe past barrier)
    COMPUTE(b0);
    unsigned short* tmp = b0; b0 = b1; b1 = b2; b2 = tmp;
  }
  asm volatile("s_waitcnt vmcnt(6)" ::: "memory");    // t = 14
  __builtin_amdgcn_s_barrier();
  __builtin_amdgcn_sched_barrier(0);
  COMPUTE(b0);
  asm volatile("s_waitcnt vmcnt(0)" ::: "memory");    // t = 15 (last: drain)
  __builtin_amdgcn_s_barrier();
  __builtin_amdgcn_sched_barrier(0);
  COMPUTE(b1);

  // epilogue: act = silu(g)*u, bf16
  const int cbase = c0base + c0loc;
#pragma unroll
  for (int mi = 0; mi < 4; ++mi) {
    int row = r0 + wr * 64 + mi * 16 + kg * 4;
#pragma unroll
    for (int ni = 0; ni < 4; ++ni) {
      int col = cbase + wc * 64 + ni * 16 + ml;
#pragma unroll
      for (int rg = 0; rg < 4; ++rg) {
        float g = accg[mi][ni][rg];
        float u = accu[mi][ni][rg];
        float a = (g / (1.0f + __expf(-g))) * u;
        act[(size_t)(row + rg) * I_DIM + col] = f2bf_rne(a);
      }
    }
  }
}

// ---------------- GEMM2 (bf16 weights, gload_lds, depth-2 counted-vmcnt pipeline) ----
// act[NROWS,I] x wb[e][CS2,I]^T -> yd[NROWS,H] (cols c0base..c0base+CS2)
__global__ __launch_bounds__(256, 2) void k_gemm2_bf(
    const unsigned short* __restrict__ act, const unsigned short* __restrict__ wb,
    const int* __restrict__ counts, unsigned short* __restrict__ yd,
    int c0base, int CS2) {
  // 3 buffers x (A 8KB | B 8KB) = 48 KB
  __shared__ unsigned short lds[3 * 8192];

  const int c0loc = blockIdx.x * 128;
  const int r0 = blockIdx.y * 128;
  const int e = r0 >> 9;
  if ((r0 & (CAP - 1)) >= min(counts[e], CAP)) return;

  const int tid = threadIdx.x;
  const int lane = tid & 63;
  const int wid = tid >> 6;
  const int wr = wid >> 1, wc = wid & 1;
  const int ml = lane & 15, kg = lane >> 4;

  const int ch = tid;
  const int kc0 = ch >> 7, rr = ch & 127;

  const unsigned short* a_src = act + (size_t)(r0 + rr) * I_DIM + kc0 * 8;
  const unsigned short* b_src = wb + (size_t)e * ((size_t)CS2 * I_DIM) +
                                (size_t)(c0loc + rr) * I_DIM + kc0 * 8;
  const int dst0 = (wid * 64) * 8;
  const int dst1 = (256 + wid * 64) * 8;

  float4v acc[4][4] = {};

  auto STAGE = [&](unsigned short* lb, int kk) {
    GLOAD_LDS16(a_src + kk,      lb + dst0);
    GLOAD_LDS16(a_src + kk + 16, lb + dst1);
    GLOAD_LDS16(b_src + kk,      lb + 4096 + dst0);
    GLOAD_LDS16(b_src + kk + 16, lb + 4096 + dst1);
  };
  auto COMPUTE = [&](const unsigned short* lb) {
    short8 af[4], bf[4];
#pragma unroll
    for (int mi = 0; mi < 4; ++mi)
      af[mi] = *(const short8*)(lb + (size_t)(kg * 128 + wr * 64 + mi * 16 + ml) * 8);
#pragma unroll
    for (int ni = 0; ni < 4; ++ni)
      bf[ni] = *(const short8*)(lb + 4096 + (size_t)(kg * 128 + wc * 64 + ni * 16 + ml) * 8);
#pragma unroll
    for (int mi = 0; mi < 4; ++mi)
#pragma unroll
      for (int ni = 0; ni < 4; ++ni)
        acc[mi][ni] = __builtin_amdgcn_mfma_f32_16x16x32_bf16(af[mi], bf[ni], acc[mi][ni], 0, 0, 0);
  };

  unsigned short* b0 = lds;
  unsigned short* b1 = lds + 8192;
  unsigned short* b2 = lds + 16384;
  STAGE(b0, 0);
  STAGE(b1, 32);
#pragma unroll 1
  for (int t = 0; t < 30; ++t) {            // NT = I/32 = 32; main body covers t=0..29
    asm volatile("s_waitcnt vmcnt(4)" ::: "memory");
    __builtin_amdgcn_s_barrier();
    __builtin_amdgcn_sched_barrier(0);
    STAGE(b2, (t + 2) * 32);
    COMPUTE(b0);
    unsigned short* tmp = b0; b0 = b1; b1 = b2; b2 = tmp;
  }
  asm volatile("s_waitcnt vmcnt(4)" ::: "memory");    // t = 30
  __builtin_amdgcn_s_barrier();
  __builtin_amdgcn_sched_barrier(0);
  COMPUTE(b0);
  asm volatile("s_waitcnt vmcnt(0)" ::: "memory");    // t = 31
  __builtin_amdgcn_s_barrier();
  __builtin_amdgcn_sched_barrier(0);
  COMPUTE(b1);

  const int cbase = c0base + c0loc;
#pragma unroll
  for (int mi = 0; mi < 4; ++mi) {
    int row = r0 + wr * 64 + mi * 16 + kg * 4;
#pragma unroll
    for (int ni = 0; ni < 4; ++ni) {
      int col = cbase + wc * 64 + ni * 16 + ml;
#pragma unroll
      for (int rg = 0; rg < 4; ++rg)
        yd[(size_t)(row + rg) * H_DIM + col] = f2bf_rne(acc[mi][ni][rg]);
    }
  }
}

// ================= FALLBACK path (convert-in-gemm), used only if ws too small =======
__global__ __launch_bounds__(256, 2) void k_gemm1(const unsigned short* __restrict__ xd,
                                                  const float* __restrict__ gup,
                                                  const int* __restrict__ counts,
                                                  unsigned short* __restrict__ act) {
  __shared__ unsigned short lds_a[4 * 128 * 8];
  __shared__ unsigned short lds_bg[4 * 128 * 8];
  __shared__ unsigned short lds_bu[4 * 128 * 8];

  const int c0 = blockIdx.x * 128;
  const int r0 = blockIdx.y * 128;
  const int e = r0 >> 9;
  if ((r0 & (CAP - 1)) >= min(counts[e], CAP)) return;

  const int tid = threadIdx.x;
  const int lane = tid & 63;
  const int wid = tid >> 6;
  const int wr = wid >> 1, wc = wid & 1;
  const int ml = lane & 15, kg = lane >> 4;

  const float* bg_base = gup + (size_t)e * (2 * I_DIM * H_DIM) + (size_t)c0 * H_DIM;
  const float* bu_base = bg_base + (size_t)I_DIM * H_DIM;

  float4v accg[4][4] = {};
  float4v accu[4][4] = {};

  for (int kk = 0; kk < H_DIM; kk += 32) {
#pragma unroll
    for (int q = 0; q < 2; ++q) {
      int ch = q * 256 + wid * 64 + lane;
      int kc = ch >> 7, row = ch & 127;
      const unsigned short* g = xd + (size_t)(r0 + row) * H_DIM + kk + kc * 8;
      unsigned short* l = lds_a + (size_t)(q * 256 + wid * 64) * 8;
      GLOAD_LDS16(g, l);
    }
#pragma unroll
    for (int q = 0; q < 2; ++q) {
      int c = q * 256 + tid;
      int n = c >> 2, kc = c & 3;
      int dst = SWZ(kc, n) * 8;
      {
        const float* g = bg_base + (size_t)n * H_DIM + kk + kc * 8;
        float4v f0 = *(const float4v*)g;
        float4v f1 = *(const float4v*)(g + 4);
        uint4v v;
        v.x = pack_bf2(f0.x, f0.y); v.y = pack_bf2(f0.z, f0.w);
        v.z = pack_bf2(f1.x, f1.y); v.w = pack_bf2(f1.z, f1.w);
        *(uint4v*)(lds_bg + dst) = v;
      }
      {
        const float* g = bu_base + (size_t)n * H_DIM + kk + kc * 8;
        float4v f0 = *(const float4v*)g;
        float4v f1 = *(const float4v*)(g + 4);
        uint4v v;
        v.x = pack_bf2(f0.x, f0.y); v.y = pack_bf2(f0.z, f0.w);
        v.z = pack_bf2(f1.x, f1.y); v.w = pack_bf2(f1.z, f1.w);
        *(uint4v*)(lds_bu + dst) = v;
      }
    }
    __syncthreads();

    short8 af[4], bgf[4], buf_[4];
#pragma unroll
    for (int mi = 0; mi < 4; ++mi)
      af[mi] = *(const short8*)(lds_a + (size_t)(kg * 128 + wr * 64 + mi * 16 + ml) * 8);
#pragma unroll
    for (int ni = 0; ni < 4; ++ni) {
      int sw = SWZ(kg, wc * 64 + ni * 16 + ml) * 8;
      bgf[ni] = *(const short8*)(lds_bg + sw);
      buf_[ni] = *(const short8*)(lds_bu + sw);
    }
#pragma unroll
    for (int mi = 0; mi < 4; ++mi)
#pragma unroll
      for (int ni = 0; ni < 4; ++ni) {
        accg[mi][ni] = __builtin_amdgcn_mfma_f32_16x16x32_bf16(af[mi], bgf[ni], accg[mi][ni], 0, 0, 0);
        accu[mi][ni] = __builtin_amdgcn_mfma_f32_16x16x32_bf16(af[mi], buf_[ni], accu[mi][ni], 0, 0, 0);
      }
    __syncthreads();
  }

#pragma unroll
  for (int mi = 0; mi < 4; ++mi) {
    int row = r0 + wr * 64 + mi * 16 + kg * 4;
#pragma unroll
    for (int ni = 0; ni < 4; ++ni) {
      int col = c0 + wc * 64 + ni * 16 + ml;
#pragma unroll
      for (int rg = 0; rg < 4; ++rg) {
        float g = accg[mi][ni][rg];
        float u = accu[mi][ni][rg];
        float a = (g / (1.0f + __expf(-g))) * u;
        act[(size_t)(row + rg) * I_DIM + col] = f2bf_rne(a);
      }
    }
  }
}

__global__ __launch_bounds__(256, 2) void k_gemm2(const unsigned short* __restrict__ act,
                                                  const float* __restrict__ dwn,
                                                  const int* __restrict__ counts,
                                                  unsigned short* __restrict__ yd) {
  __shared__ unsigned short lds_a[4 * 128 * 8];
  __shared__ unsigned short lds_b[4 * 128 * 8];

  const int c0 = blockIdx.x * 128;
  const int r0 = blockIdx.y * 128;
  const int e = r0 >> 9;
  if ((r0 & (CAP - 1)) >= min(counts[e], CAP)) return;

  const int tid = threadIdx.x;
  const int lane = tid & 63;
  const int wid = tid >> 6;
  const int wr = wid >> 1, wc = wid & 1;
  const int ml = lane & 15, kg = lane >> 4;

  const float* b_base = dwn + (size_t)e * (H_DIM * I_DIM) + (size_t)c0 * I_DIM;

  float4v acc[4][4] = {};

  for (int kk = 0; kk < I_DIM; kk += 32) {
#pragma unroll
    for (int q = 0; q < 2; ++q) {
      int ch = q * 256 + wid * 64 + lane;
      int kc = ch >> 7, row = ch & 127;
      const unsigned short* g = act + (size_t)(r0 + row) * I_DIM + kk + kc * 8;
      unsigned short* l = lds_a + (size_t)(q * 256 + wid * 64) * 8;
      GLOAD_LDS16(g, l);
    }
#pragma unroll
    for (int q = 0; q < 2; ++q) {
      int cc = q * 256 + tid;
      int n = cc >> 2, kc = cc & 3;
      const float* g = b_base + (size_t)n * I_DIM + kk + kc * 8;
      float4v f0 = *(const float4v*)g;
      float4v f1 = *(const float4v*)(g + 4);
      uint4v v;
      v.x = pack_bf2(f0.x, f0.y); v.y = pack_bf2(f0.z, f0.w);
      v.z = pack_bf2(f1.x, f1.y); v.w = pack_bf2(f1.z, f1.w);
      *(uint4v*)(lds_b + SWZ(kc, n) * 8) = v;
    }
    __syncthreads();

    short8 af[4], bf[4];
#pragma unroll
    for (int mi = 0; mi < 4; ++mi)
      af[mi] = *(const short8*)(lds_a + (size_t)(kg * 128 + wr * 64 + mi * 16 + ml) * 8);
#pragma unroll
    for (int ni = 0; ni < 4; ++ni)
      bf[ni] = *(const short8*)(lds_b + SWZ(kg, wc * 64 + ni * 16 + ml) * 8);
#pragma unroll
    for (int mi = 0; mi < 4; ++mi)
#pragma unroll
      for (int ni = 0; ni < 4; ++ni)
        acc[mi][ni] = __builtin_amdgcn_mfma_f32_16x16x32_bf16(af[mi], bf[ni], acc[mi][ni], 0, 0, 0);
    __syncthreads();
  }

#pragma unroll
  for (int mi = 0; mi < 4; ++mi) {
    int row = r0 + wr * 64 + mi * 16 + kg * 4;
#pragma unroll
    for (int ni = 0; ni < 4; ++ni) {
      int col = c0 + wc * 64 + ni * 16 + ml;
#pragma unroll
      for (int rg = 0; rg < 4; ++rg)
        yd[(size_t)(row + rg) * H_DIM + col] = f2bf_rne(acc[mi][ni][rg]);
    }
  }
}

// ---------------- combine: out[t] = sum_k w[t,k] * yd[inv[t,k]] ----------------
__global__ void k_combine(const unsigned short* __restrict__ yd, const int* __restrict__ inv,
                          const float* __restrict__ wts, float* __restrict__ out) {
  const int t = blockIdx.x * 4 + (threadIdx.x >> 6);  // one wave per token
  const int lane = threadIdx.x & 63;
  const int i0 = 2 * t, i1 = 2 * t + 1;
  const int r0 = inv[i0], r1 = inv[i1];
  float o[8] = {0.f, 0.f, 0.f, 0.f, 0.f, 0.f, 0.f, 0.f};
  if (r0 >= 0) {
    float w = wts[i0];
    short8 y = *(const short8*)(yd + (size_t)r0 * H_DIM + lane * 8);
#pragma unroll
    for (int j = 0; j < 8; ++j) o[j] += w * bf2f((unsigned short)y[j]);
  }
  if (r1 >= 0) {
    float w = wts[i1];
    short8 y = *(const short8*)(yd + (size_t)r1 * H_DIM + lane * 8);
#pragma unroll
    for (int j = 0; j < 8; ++j) o[j] += w * bf2f((unsigned short)y[j]);
  }
  float4v v0 = {o[0], o[1], o[2], o[3]};
  float4v v1 = {o[4], o[5], o[6], o[7]};
  float4v* dst = (float4v*)(out + (size_t)t * H_DIM + lane * 8);
  dst[0] = v0;
  dst[1] = v1;
}

extern "C" void kernel_launch(void* const* d_in, const int* in_sizes, int n_in,
                              void* d_out, int out_size, void* d_ws, size_t ws_size,
                              hipStream_t stream) {
  const float* hs  = (const float*)d_in[0];  // [T,H]
  const int*   idx = (const int*)d_in[1];    // [T,K]
  const float* wts = (const float*)d_in[2];  // [T,K]
  const float* gup = (const float*)d_in[3];  // [E,2I,H]
  const float* dwn = (const float*)d_in[4];  // [E,H,I]
  float* out = (float*)d_out;                // [T,H]

  char* ws = (char*)d_ws;
  int* counts       = (int*)ws;                             // 128 B used
  int* inv          = (int*)(ws + 1024);                    // 32 KB
  int* slot_token   = (int*)(ws + 1024 + 32768);            // 64 KB
  unsigned short* xd  = (unsigned short*)(ws + 131072);     // 16.8 MB
  unsigned short* act = xd + (size_t)NROWS * H_DIM;         // 33.6 MB
  unsigned short* yd  = xd;  // xd dead after gemm1; alias
  const size_t off_wbuf = 131072 + (size_t)NROWS * H_DIM * 2 + (size_t)NROWS * I_DIM * 2;

  // pick weight-buffer split so bf16 weights fit in workspace
  int NS = 0;
  for (int cand = 1; cand <= 8; cand <<= 1) {
    size_t need = (size_t)E_NUM * 2 * (size_t)(I_DIM / cand) * H_DIM * 2;  // bf16 gate+up chunk
    if (off_wbuf + need <= ws_size) { NS = cand; break; }
  }

  hipMemsetAsync(counts, 0, E_NUM * sizeof(int), stream);

  if (NS) {
    unsigned short* wbuf = (unsigned short*)(ws + off_wbuf);
    const int CS = I_DIM / NS;
    // convert first split(s)' weights before routing so wbuf is L3-hot at gemm time
    if (NS == 1) {
      k_wconv<<<dim3(CS * H_DIM / 2048, E_NUM), 256, 0, stream>>>(
          gup, wbuf, (size_t)2 * I_DIM * H_DIM, (size_t)2 * CS * H_DIM, CS * H_DIM);
      k_wconv<<<dim3(CS * H_DIM / 2048, E_NUM), 256, 0, stream>>>(
          gup + (size_t)I_DIM * H_DIM, wbuf + (size_t)CS * H_DIM,
          (size_t)2 * I_DIM * H_DIM, (size_t)2 * CS * H_DIM, CS * H_DIM);
    }
    k_route<<<NPAIR / 256, 256, 0, stream>>>(idx, counts, slot_token, inv);
    k_gather<<<NROWS / 4, 256, 0, stream>>>(hs, counts, slot_token, xd);

    for (int s = 0; s < NS; ++s) {
      if (NS > 1) {
        k_wconv<<<dim3(CS * H_DIM / 2048, E_NUM), 256, 0, stream>>>(
            gup + (size_t)s * CS * H_DIM, wbuf,
            (size_t)2 * I_DIM * H_DIM, (size_t)2 * CS * H_DIM, CS * H_DIM);
        k_wconv<<<dim3(CS * H_DIM / 2048, E_NUM), 256, 0, stream>>>(
            gup + (size_t)(I_DIM + s * CS) * H_DIM, wbuf + (size_t)CS * H_DIM,
            (size_t)2 * I_DIM * H_DIM, (size_t)2 * CS * H_DIM, CS * H_DIM);
      }
      dim3 g1(CS / 128, NROWS / 128);
      k_gemm1_bf<<<g1, 256, 0, stream>>>(xd, wbuf, counts, act, s * CS, CS);
    }

    const int NS2 = (NS > 1) ? NS / 2 : 1;
    const int CS2 = H_DIM / NS2;
    for (int s = 0; s < NS2; ++s) {
      k_wconv<<<dim3(CS2 * I_DIM / 2048, E_NUM), 256, 0, stream>>>(
          dwn + (size_t)s * CS2 * I_DIM, wbuf,
          (size_t)H_DIM * I_DIM, (size_t)CS2 * I_DIM, CS2 * I_DIM);
      dim3 g2(CS2 / 128, NROWS / 128);
      k_gemm2_bf<<<g2, 256, 0, stream>>>(act, wbuf, counts, yd, s * CS2, CS2);
    }
  } else {
    // fallback: original convert-in-gemm path (fits in 48.2 MB)
    k_route<<<NPAIR / 256, 256, 0, stream>>>(idx, counts, slot_token, inv);
    k_gather<<<NROWS / 4, 256, 0, stream>>>(hs, counts, slot_token, xd);
    dim3 g1(I_DIM / 128, NROWS / 128);
    k_gemm1<<<g1, 256, 0, stream>>>(xd, gup, counts, act);
    dim3 g2(H_DIM / 128, NROWS / 128);
    k_gemm2<<<g2, 256, 0, stream>>>(act, dwn, counts, yd);
  }

  k_combine<<<T_TOK / 4, 256, 0, stream>>>(yd, inv, wts, out);
}

// Round 2
// 366.099 us; speedup vs baseline: 1.0384x; 1.0384x over previous
//
#include <hip/hip_runtime.h>

#define T_TOK 4096
#define H_DIM 512
#define I_DIM 1024
#define E_NUM 32
#define KTOP  2
#define CAP   512
#define NROWS (E_NUM * CAP)    // 16384
#define NPAIR (T_TOK * KTOP)   // 8192

typedef __attribute__((ext_vector_type(8))) short short8;    // 8 bf16 = 4 VGPRs
typedef __attribute__((ext_vector_type(4))) float float4v;
typedef __attribute__((ext_vector_type(4))) unsigned int uint4v;

__device__ __forceinline__ unsigned short f2bf_rne(float f) {
  unsigned int u = __float_as_uint(f);
  u += 0x7FFFu + ((u >> 16) & 1u);
  return (unsigned short)(u >> 16);
}
__device__ __forceinline__ unsigned int pack_bf2(float a, float b) {
  return (unsigned int)f2bf_rne(a) | ((unsigned int)f2bf_rne(b) << 16);
}
__device__ __forceinline__ float bf2f(unsigned short s) {
  return __uint_as_float(((unsigned int)s) << 16);
}

#define GLOAD_LDS16(gptr, lptr)                                                         \
  __builtin_amdgcn_global_load_lds((const __attribute__((address_space(1))) unsigned int*)(gptr), \
                                   (__attribute__((address_space(3))) unsigned int*)(lptr), 16, 0, 0)

// B chunk index: kc in [0,4), n in [0,64). XOR makes the 4 kc-groups of a wave's
// ds_write_b128 land on disjoint banks (conflict-free), and permutes the read
// side only within each 16-lane contiguous run (also conflict-free).
#define BCH(kc, n) ((kc) * 64 + ((n) ^ (kc)))

// ---------------- routing ----------------
__global__ void k_route(const int* __restrict__ idx, int* __restrict__ counts,
                        int* __restrict__ slot_token, int* __restrict__ inv) {
  int i = blockIdx.x * 256 + threadIdx.x;
  if (i >= NPAIR) return;
  int e = idx[i];
  int p = atomicAdd(counts + e, 1);
  if (p < CAP) {
    slot_token[e * CAP + p] = i >> 1;  // KTOP == 2
    inv[i] = e * CAP + p;
  } else {
    inv[i] = -1;
  }
}

// ---------------- gather tokens -> bf16 dispatch buffer (early-exit padded rows) ----
__global__ void k_gather(const float* __restrict__ hs, const int* __restrict__ counts,
                         const int* __restrict__ slot_token, unsigned short* __restrict__ xd) {
  const int r = blockIdx.x * 4 + (threadIdx.x >> 6);  // one wave per row
  const int lane = threadIdx.x & 63;
  const int e = r >> 9;
  const int p = r & (CAP - 1);
  const int cnt = min(counts[e], CAP);
  if (p >= ((cnt + 127) & ~127)) return;  // beyond last active tile: never read
  uint4v v = {0u, 0u, 0u, 0u};
  if (p < cnt) {
    const int t = slot_token[r];
    const float4v* src = (const float4v*)(hs + (size_t)t * H_DIM);
    float4v f0 = src[lane * 2];
    float4v f1 = src[lane * 2 + 1];
    v.x = pack_bf2(f0.x, f0.y);
    v.y = pack_bf2(f0.z, f0.w);
    v.z = pack_bf2(f1.x, f1.y);
    v.w = pack_bf2(f1.z, f1.w);
  }
  *(uint4v*)(xd + (size_t)r * H_DIM + lane * 8) = v;
}

// ---------------- GEMM1: xd[NROWS,H] x gate_up[E,2I,H]^T -> silu(g)*u -> act[NROWS,I]
// 128-row x 64-col tiles, double-buffered LDS, async-split B staging (T14),
// A via global_load_lds. One __syncthreads per K-step.
__global__ __launch_bounds__(256, 3) void k_gemm1(const unsigned short* __restrict__ xd,
                                                  const float* __restrict__ gup,
                                                  const int* __restrict__ counts,
                                                  unsigned short* __restrict__ act) {
  // per buffer: A = 4kc x 128row x 8 bf16 = 8KB; Bg = Bu = 4kc x 64n x 8 = 4KB -> 2x16KB = 32KB
  __shared__ unsigned short lds_a[2][4096];
  __shared__ unsigned short lds_bg[2][2048];
  __shared__ unsigned short lds_bu[2][2048];

  const int c0 = blockIdx.x * 64;   // gate col base (0..I)
  const int r0 = blockIdx.y * 128;  // row base
  const int e = r0 >> 9;
  if ((r0 & (CAP - 1)) >= min(counts[e], CAP)) return;  // fully-padded tile

  const int tid = threadIdx.x;
  const int lane = tid & 63;
  const int wid = tid >> 6;
  const int wr = wid >> 1, wc = wid & 1;   // wave tile: 64 rows x 32 cols
  const int ml = lane & 15, kg = lane >> 4;

  // A staging: chunk ch in {tid, 256+tid}; kc = ch>>7, row = ch&127
  const int rowA = tid & 127;
  const int kcA = tid >> 7;
  const unsigned short* aA = xd + (size_t)(r0 + rowA) * H_DIM + kcA * 8;
  const int ldsA0 = (wid * 64) * 8;        // wave-uniform base; DMA adds lane*16B
  const int ldsA1 = (256 + wid * 64) * 8;

  // B staging: row n = tid>>2 (0..63), kc = tid&3 -> 8 consecutive fp32 (coalesced 128B/row)
  const int nB = tid >> 2, kcB = tid & 3;
  const float* gB = gup + (size_t)e * (2 * I_DIM * H_DIM) + (size_t)(c0 + nB) * H_DIM + kcB * 8;
  const float* uB = gB + (size_t)I_DIM * H_DIM;
  const int bChunk = BCH(kcB, nB) * 8;

  float4v accg[4][2] = {};
  float4v accu[4][2] = {};
  float4v rg0, rg1, ru0, ru1;

  auto LOADB = [&](int kk) {
    rg0 = *(const float4v*)(gB + kk);
    rg1 = *(const float4v*)(gB + kk + 4);
    ru0 = *(const float4v*)(uB + kk);
    ru1 = *(const float4v*)(uB + kk + 4);
  };
  auto STOREB = [&](unsigned short* lg, unsigned short* lu) {
    uint4v vg, vu;
    vg.x = pack_bf2(rg0.x, rg0.y); vg.y = pack_bf2(rg0.z, rg0.w);
    vg.z = pack_bf2(rg1.x, rg1.y); vg.w = pack_bf2(rg1.z, rg1.w);
    vu.x = pack_bf2(ru0.x, ru0.y); vu.y = pack_bf2(ru0.z, ru0.w);
    vu.z = pack_bf2(ru1.x, ru1.y); vu.w = pack_bf2(ru1.z, ru1.w);
    *(uint4v*)(lg + bChunk) = vg;
    *(uint4v*)(lu + bChunk) = vu;
  };
  auto STAGEA = [&](unsigned short* la, int kk) {
    GLOAD_LDS16(aA + kk, la + ldsA0);
    GLOAD_LDS16(aA + kk + 16, la + ldsA1);
  };
  auto COMPUTE = [&](const unsigned short* la, const unsigned short* lg,
                     const unsigned short* lu) {
    short8 af[4], bg[2], bu[2];
#pragma unroll
    for (int mi = 0; mi < 4; ++mi)
      af[mi] = *(const short8*)(la + (kg * 128 + wr * 64 + mi * 16 + ml) * 8);
#pragma unroll
    for (int ni = 0; ni < 2; ++ni) {
      const int o = BCH(kg, wc * 32 + ni * 16 + ml) * 8;
      bg[ni] = *(const short8*)(lg + o);
      bu[ni] = *(const short8*)(lu + o);
    }
#pragma unroll
    for (int mi = 0; mi < 4; ++mi)
#pragma unroll
      for (int ni = 0; ni < 2; ++ni) {
        accg[mi][ni] = __builtin_amdgcn_mfma_f32_16x16x32_bf16(af[mi], bg[ni], accg[mi][ni], 0, 0, 0);
        accu[mi][ni] = __builtin_amdgcn_mfma_f32_16x16x32_bf16(af[mi], bu[ni], accu[mi][ni], 0, 0, 0);
      }
  };

  LOADB(0);
  STAGEA(lds_a[0], 0);
  STOREB(lds_bg[0], lds_bu[0]);
  __syncthreads();
#pragma unroll 1
  for (int t = 0; t < 15; ++t) {           // NT = H/32 = 16
    const int cur = t & 1, nxt = cur ^ 1;
    LOADB((t + 1) * 32);                   // issue early: latency hides under MFMA
    STAGEA(lds_a[nxt], (t + 1) * 32);      // async DMA; drained by the barrier
    COMPUTE(lds_a[cur], lds_bg[cur], lds_bu[cur]);
    STOREB(lds_bg[nxt], lds_bu[nxt]);      // write late (vmcnt for regs lands here)
    __syncthreads();
  }
  COMPUTE(lds_a[1], lds_bg[1], lds_bu[1]); // t = 15

  // epilogue: act = silu(g)*u, bf16
#pragma unroll
  for (int mi = 0; mi < 4; ++mi) {
    const int row = r0 + wr * 64 + mi * 16 + kg * 4;
#pragma unroll
    for (int ni = 0; ni < 2; ++ni) {
      const int col = c0 + wc * 32 + ni * 16 + ml;
#pragma unroll
      for (int rj = 0; rj < 4; ++rj) {
        float g = accg[mi][ni][rj];
        float u = accu[mi][ni][rj];
        float a = (g / (1.0f + __expf(-g))) * u;
        act[(size_t)(row + rj) * I_DIM + col] = f2bf_rne(a);
      }
    }
  }
}

// ---------------- GEMM2: act[NROWS,I] x down[E,H,I]^T -> yd[NROWS,H] bf16 ----
__global__ __launch_bounds__(256, 3) void k_gemm2(const unsigned short* __restrict__ act,
                                                  const float* __restrict__ dwn,
                                                  const int* __restrict__ counts,
                                                  unsigned short* __restrict__ yd) {
  // per buffer: A 8KB + B 4KB -> 2x12KB = 24KB
  __shared__ unsigned short lds_a[2][4096];
  __shared__ unsigned short lds_b[2][2048];

  const int c0 = blockIdx.x * 64;   // h col base (0..H)
  const int r0 = blockIdx.y * 128;
  const int e = r0 >> 9;
  if ((r0 & (CAP - 1)) >= min(counts[e], CAP)) return;

  const int tid = threadIdx.x;
  const int lane = tid & 63;
  const int wid = tid >> 6;
  const int wr = wid >> 1, wc = wid & 1;
  const int ml = lane & 15, kg = lane >> 4;

  const int rowA = tid & 127;
  const int kcA = tid >> 7;
  const unsigned short* aA = act + (size_t)(r0 + rowA) * I_DIM + kcA * 8;
  const int ldsA0 = (wid * 64) * 8;
  const int ldsA1 = (256 + wid * 64) * 8;

  const int nB = tid >> 2, kcB = tid & 3;
  const float* bB = dwn + (size_t)e * (H_DIM * I_DIM) + (size_t)(c0 + nB) * I_DIM + kcB * 8;
  const int bChunk = BCH(kcB, nB) * 8;

  float4v acc[4][2] = {};
  float4v rb0, rb1;

  auto LOADB = [&](int kk) {
    rb0 = *(const float4v*)(bB + kk);
    rb1 = *(const float4v*)(bB + kk + 4);
  };
  auto STOREB = [&](unsigned short* lb) {
    uint4v v;
    v.x = pack_bf2(rb0.x, rb0.y); v.y = pack_bf2(rb0.z, rb0.w);
    v.z = pack_bf2(rb1.x, rb1.y); v.w = pack_bf2(rb1.z, rb1.w);
    *(uint4v*)(lb + bChunk) = v;
  };
  auto STAGEA = [&](unsigned short* la, int kk) {
    GLOAD_LDS16(aA + kk, la + ldsA0);
    GLOAD_LDS16(aA + kk + 16, la + ldsA1);
  };
  auto COMPUTE = [&](const unsigned short* la, const unsigned short* lb) {
    short8 af[4], bf[2];
#pragma unroll
    for (int mi = 0; mi < 4; ++mi)
      af[mi] = *(const short8*)(la + (kg * 128 + wr * 64 + mi * 16 + ml) * 8);
#pragma unroll
    for (int ni = 0; ni < 2; ++ni)
      bf[ni] = *(const short8*)(lb + BCH(kg, wc * 32 + ni * 16 + ml) * 8);
#pragma unroll
    for (int mi = 0; mi < 4; ++mi)
#pragma unroll
      for (int ni = 0; ni < 2; ++ni)
        acc[mi][ni] = __builtin_amdgcn_mfma_f32_16x16x32_bf16(af[mi], bf[ni], acc[mi][ni], 0, 0, 0);
  };

  LOADB(0);
  STAGEA(lds_a[0], 0);
  STOREB(lds_b[0]);
  __syncthreads();
#pragma unroll 1
  for (int t = 0; t < 31; ++t) {           // NT = I/32 = 32
    const int cur = t & 1, nxt = cur ^ 1;
    LOADB((t + 1) * 32);
    STAGEA(lds_a[nxt], (t + 1) * 32);
    COMPUTE(lds_a[cur], lds_b[cur]);
    STOREB(lds_b[nxt]);
    __syncthreads();
  }
  COMPUTE(lds_a[1], lds_b[1]);             // t = 31

#pragma unroll
  for (int mi = 0; mi < 4; ++mi) {
    const int row = r0 + wr * 64 + mi * 16 + kg * 4;
#pragma unroll
    for (int ni = 0; ni < 2; ++ni) {
      const int col = c0 + wc * 32 + ni * 16 + ml;
#pragma unroll
      for (int rj = 0; rj < 4; ++rj)
        yd[(size_t)(row + rj) * H_DIM + col] = f2bf_rne(acc[mi][ni][rj]);
    }
  }
}

// ---------------- combine: out[t] = sum_k w[t,k] * yd[inv[t,k]] ----------------
__global__ void k_combine(const unsigned short* __restrict__ yd, const int* __restrict__ inv,
                          const float* __restrict__ wts, float* __restrict__ out) {
  const int t = blockIdx.x * 4 + (threadIdx.x >> 6);  // one wave per token
  const int lane = threadIdx.x & 63;
  const int i0 = 2 * t, i1 = 2 * t + 1;
  const int r0 = inv[i0], r1 = inv[i1];
  float o[8] = {0.f, 0.f, 0.f, 0.f, 0.f, 0.f, 0.f, 0.f};
  if (r0 >= 0) {
    float w = wts[i0];
    short8 y = *(const short8*)(yd + (size_t)r0 * H_DIM + lane * 8);
#pragma unroll
    for (int j = 0; j < 8; ++j) o[j] += w * bf2f((unsigned short)y[j]);
  }
  if (r1 >= 0) {
    float w = wts[i1];
    short8 y = *(const short8*)(yd + (size_t)r1 * H_DIM + lane * 8);
#pragma unroll
    for (int j = 0; j < 8; ++j) o[j] += w * bf2f((unsigned short)y[j]);
  }
  float4v v0 = {o[0], o[1], o[2], o[3]};
  float4v v1 = {o[4], o[5], o[6], o[7]};
  float4v* dst = (float4v*)(out + (size_t)t * H_DIM + lane * 8);
  dst[0] = v0;
  dst[1] = v1;
}

extern "C" void kernel_launch(void* const* d_in, const int* in_sizes, int n_in,
                              void* d_out, int out_size, void* d_ws, size_t ws_size,
                              hipStream_t stream) {
  const float* hs  = (const float*)d_in[0];  // [T,H]
  const int*   idx = (const int*)d_in[1];    // [T,K]
  const float* wts = (const float*)d_in[2];  // [T,K]
  const float* gup = (const float*)d_in[3];  // [E,2I,H]
  const float* dwn = (const float*)d_in[4];  // [E,H,I]
  float* out = (float*)d_out;                // [T,H]

  char* ws = (char*)d_ws;
  int* counts       = (int*)ws;                             // 128 B used
  int* inv          = (int*)(ws + 1024);                    // 32 KB
  int* slot_token   = (int*)(ws + 1024 + 32768);            // 64 KB
  unsigned short* xd  = (unsigned short*)(ws + 131072);     // 16.8 MB
  unsigned short* act = xd + (size_t)NROWS * H_DIM;         // 33.6 MB
  unsigned short* yd  = xd;  // xd is dead after gemm1; alias

  hipMemsetAsync(counts, 0, E_NUM * sizeof(int), stream);
  k_route<<<NPAIR / 256, 256, 0, stream>>>(idx, counts, slot_token, inv);
  k_gather<<<NROWS / 4, 256, 0, stream>>>(hs, counts, slot_token, xd);
  dim3 g1(I_DIM / 64, NROWS / 128);   // 16 x 128 = 2048 blocks
  k_gemm1<<<g1, 256, 0, stream>>>(xd, gup, counts, act);
  dim3 g2(H_DIM / 64, NROWS / 128);   // 8 x 128 = 1024 blocks
  k_gemm2<<<g2, 256, 0, stream>>>(act, dwn, counts, yd);
  k_combine<<<T_TOK / 4, 256, 0, stream>>>(yd, inv, wts, out);
}

// Round 3
// 340.081 us; speedup vs baseline: 1.1178x; 1.0765x over previous
//
#include <hip/hip_runtime.h>

#define T_TOK 4096
#define H_DIM 512
#define I_DIM 1024
#define E_NUM 32
#define KTOP  2
#define CAP   512
#define NROWS (E_NUM * CAP)    // 16384
#define NPAIR (T_TOK * KTOP)   // 8192

typedef __attribute__((ext_vector_type(8))) short short8;    // 8 bf16 = 4 VGPRs
typedef __attribute__((ext_vector_type(4))) float float4v;
typedef __attribute__((ext_vector_type(4))) unsigned int uint4v;

typedef union { short8 s; uint4v u; } frag_u;

__device__ __forceinline__ unsigned short f2bf_rne(float f) {
  unsigned int u = __float_as_uint(f);
  u += 0x7FFFu + ((u >> 16) & 1u);
  return (unsigned short)(u >> 16);
}
__device__ __forceinline__ unsigned int pack_bf2(float a, float b) {
  return (unsigned int)f2bf_rne(a) | ((unsigned int)f2bf_rne(b) << 16);
}
__device__ __forceinline__ float bf2f(unsigned short s) {
  return __uint_as_float(((unsigned int)s) << 16);
}
// HW packed fp32->bf16 RNE convert: D[15:0]=cvt(a), D[31:16]=cvt(b)
__device__ __forceinline__ unsigned int cvtpk(float a, float b) {
  unsigned int d;
  asm("v_cvt_pk_bf16_f32 %0, %1, %2" : "=v"(d) : "v"(a), "v"(b));
  return d;
}

#define GLOAD_LDS16(gptr, lptr)                                                         \
  __builtin_amdgcn_global_load_lds((const __attribute__((address_space(1))) unsigned int*)(gptr), \
                                   (__attribute__((address_space(3))) unsigned int*)(lptr), 16, 0, 0)

// ---------------- routing ----------------
__global__ void k_route(const int* __restrict__ idx, int* __restrict__ counts,
                        int* __restrict__ slot_token, int* __restrict__ inv) {
  int i = blockIdx.x * 256 + threadIdx.x;
  if (i >= NPAIR) return;
  int e = idx[i];
  int p = atomicAdd(counts + e, 1);
  if (p < CAP) {
    slot_token[e * CAP + p] = i >> 1;  // KTOP == 2
    inv[i] = e * CAP + p;
  } else {
    inv[i] = -1;
  }
}

// ---------------- gather tokens -> bf16 dispatch buffer (early-exit padded rows) ----
__global__ void k_gather(const float* __restrict__ hs, const int* __restrict__ counts,
                         const int* __restrict__ slot_token, unsigned short* __restrict__ xd) {
  const int r = blockIdx.x * 4 + (threadIdx.x >> 6);  // one wave per row
  const int lane = threadIdx.x & 63;
  const int e = r >> 9;
  const int p = r & (CAP - 1);
  const int cnt = min(counts[e], CAP);
  if (p >= ((cnt + 127) & ~127)) return;  // beyond last active tile: never read
  uint4v v = {0u, 0u, 0u, 0u};
  if (p < cnt) {
    const int t = slot_token[r];
    const float4v* src = (const float4v*)(hs + (size_t)t * H_DIM);
    float4v f0 = src[lane * 2];
    float4v f1 = src[lane * 2 + 1];
    v.x = pack_bf2(f0.x, f0.y);
    v.y = pack_bf2(f0.z, f0.w);
    v.z = pack_bf2(f1.x, f1.y);
    v.w = pack_bf2(f1.z, f1.w);
  }
  *(uint4v*)(xd + (size_t)r * H_DIM + lane * 8) = v;
}

// ---------------- GEMM1: xd[NROWS,H] x gate_up[E,2I,H]^T -> silu(g)*u -> act[NROWS,I]
// 128x64 tiles. ALL operands staged via global_load_lds (A bf16, B fp32 with
// pre-swizzled source). 3-buffer depth-2 counted-vmcnt pipeline (T3+T4).
// B converted to bf16 at fragment-read time with v_cvt_pk_bf16_f32.
// Expert<->XCD affinity swizzle: all 64 blocks of an expert on one XCD (L2 reuse).
__global__ __launch_bounds__(256, 2) void k_gemm1(const unsigned short* __restrict__ xd,
                                                  const float* __restrict__ gup,
                                                  const int* __restrict__ counts,
                                                  unsigned short* __restrict__ act) {
  // per buffer (ushort units): A bf16 4096 (8KB) | Bg fp32 4096 (8KB) | Bu fp32 4096 (8KB)
  __shared__ unsigned short lds[3 * 12288];

  // expert->XCD affinity: hw assigns wg i -> XCD i%8 (round robin)
  const int bid = blockIdx.x;           // 2048 blocks
  const int xcd = bid & 7, slot = bid >> 3;       // slot 0..255
  const int e = xcd * 4 + (slot >> 6);            // 4 experts per XCD
  const int sub = slot & 63;                      // 64 blocks per expert
  const int c0 = (sub & 15) * 64;                 // 16 col tiles over I
  const int rt = sub >> 4;                        // 4 row tiles per expert
  const int r0 = e * CAP + rt * 128;
  if (rt * 128 >= min(counts[e], CAP)) return;    // fully-padded tile

  const int tid = threadIdx.x;
  const int lane = tid & 63;
  const int wid = tid >> 6;
  const int wr = wid >> 1, wc = wid & 1;   // wave tile: 64 rows x 32 cols
  const int ml = lane & 15, kg = lane >> 4;

  // A staging: chunk ch in {tid, 256+tid}: kc = ch>>7 (8-bf16 k-chunks), row = ch&127
  const int rowA = tid & 127, kcA = tid >> 7;
  const unsigned short* a_src = xd + (size_t)(r0 + rowA) * H_DIM + kcA * 8;
  const int dA0 = (wid * 64) * 8;          // wave-uniform LDS base; DMA adds lane*16B
  const int dA1 = (256 + wid * 64) * 8;

  // B staging (fp32): chunk ch in {tid, 256+tid}: n = ch>>3 (0..63), kcs = ch&7.
  // LDS chunk (kcs,n) at index n*8+kcs holds global k-chunk kc = kcs ^ (n&7)
  // (pre-swizzled source; linear DMA dest). 4 fp32 per 16B chunk.
  const int nB0 = tid >> 3, kcsB = tid & 7;
  const int kcB0 = kcsB ^ (nB0 & 7);               // n1 = n0+32 has same n&7 -> same kc
  const float* g_row0 = gup + (size_t)e * (2 * I_DIM * H_DIM) + (size_t)(c0 + nB0) * H_DIM + kcB0 * 4;
  const float* g_row1 = g_row0 + (size_t)32 * H_DIM;
  const float* u_row0 = g_row0 + (size_t)I_DIM * H_DIM;
  const float* u_row1 = u_row0 + (size_t)32 * H_DIM;
  const int dB0 = 4096 + (wid * 64) * 8;   // Bg group0 (chunks 0..255)
  const int dB1 = 4096 + (256 + wid * 64) * 8;
  const int dU0 = 8192 + (wid * 64) * 8;
  const int dU1 = 8192 + (256 + wid * 64) * 8;

  float4v accg[4][2] = {};
  float4v accu[4][2] = {};

  auto STAGE = [&](unsigned short* lb, int kk) {
    GLOAD_LDS16(a_src + kk, lb + dA0);
    GLOAD_LDS16(a_src + kk + 16, lb + dA1);
    GLOAD_LDS16(g_row0 + kk, lb + dB0);
    GLOAD_LDS16(g_row1 + kk, lb + dB1);
    GLOAD_LDS16(u_row0 + kk, lb + dU0);
    GLOAD_LDS16(u_row1 + kk, lb + dU1);
  };
  auto COMPUTE = [&](const unsigned short* lb) {
    short8 af[4];
#pragma unroll
    for (int mi = 0; mi < 4; ++mi)
      af[mi] = *(const short8*)(lb + (kg * 128 + wr * 64 + mi * 16 + ml) * 8);
    frag_u bg[2], bu[2];
#pragma unroll
    for (int ni = 0; ni < 2; ++ni) {
      const int n = wc * 32 + ni * 16 + ml;
      const int i0 = (n * 8 + ((2 * kg) ^ (n & 7))) * 8;        // chunk -> ushort offset
      const int i1 = (n * 8 + ((2 * kg + 1) ^ (n & 7))) * 8;
      float4v g0 = *(const float4v*)(lb + 4096 + i0);
      float4v g1 = *(const float4v*)(lb + 4096 + i1);
      bg[ni].u.x = cvtpk(g0.x, g0.y); bg[ni].u.y = cvtpk(g0.z, g0.w);
      bg[ni].u.z = cvtpk(g1.x, g1.y); bg[ni].u.w = cvtpk(g1.z, g1.w);
      float4v u0 = *(const float4v*)(lb + 8192 + i0);
      float4v u1 = *(const float4v*)(lb + 8192 + i1);
      bu[ni].u.x = cvtpk(u0.x, u0.y); bu[ni].u.y = cvtpk(u0.z, u0.w);
      bu[ni].u.z = cvtpk(u1.x, u1.y); bu[ni].u.w = cvtpk(u1.z, u1.w);
    }
#pragma unroll
    for (int mi = 0; mi < 4; ++mi)
#pragma unroll
      for (int ni = 0; ni < 2; ++ni) {
        accg[mi][ni] = __builtin_amdgcn_mfma_f32_16x16x32_bf16(af[mi], bg[ni].s, accg[mi][ni], 0, 0, 0);
        accu[mi][ni] = __builtin_amdgcn_mfma_f32_16x16x32_bf16(af[mi], bu[ni].s, accu[mi][ni], 0, 0, 0);
      }
  };

  unsigned short* b0 = lds;
  unsigned short* b1 = lds + 12288;
  unsigned short* b2 = lds + 24576;
  STAGE(b0, 0);
  STAGE(b1, 32);
#pragma unroll 1
  for (int t = 0; t < 14; ++t) {           // NT = H/32 = 16; main body t=0..13
    asm volatile("s_waitcnt vmcnt(6)" ::: "memory");  // tile t landed; t+1 in flight
    __builtin_amdgcn_s_barrier();
    __builtin_amdgcn_sched_barrier(0);
    STAGE(b2, (t + 2) * 32);               // b2 was computed at t-1: safe past barrier
    COMPUTE(b0);
    unsigned short* tmp = b0; b0 = b1; b1 = b2; b2 = tmp;
  }
  asm volatile("s_waitcnt vmcnt(6)" ::: "memory");    // t = 14
  __builtin_amdgcn_s_barrier();
  __builtin_amdgcn_sched_barrier(0);
  COMPUTE(b0);
  asm volatile("s_waitcnt vmcnt(0)" ::: "memory");    // t = 15 (drain)
  __builtin_amdgcn_s_barrier();
  __builtin_amdgcn_sched_barrier(0);
  COMPUTE(b1);

  // epilogue: act = silu(g)*u, bf16
#pragma unroll
  for (int mi = 0; mi < 4; ++mi) {
    const int row = r0 + wr * 64 + mi * 16 + kg * 4;
#pragma unroll
    for (int ni = 0; ni < 2; ++ni) {
      const int col = c0 + wc * 32 + ni * 16 + ml;
#pragma unroll
      for (int rj = 0; rj < 4; ++rj) {
        float g = accg[mi][ni][rj];
        float u = accu[mi][ni][rj];
        float a = (g / (1.0f + __expf(-g))) * u;
        act[(size_t)(row + rj) * I_DIM + col] = f2bf_rne(a);
      }
    }
  }
}

// ---------------- GEMM2: act[NROWS,I] x down[E,H,I]^T -> yd[NROWS,H] bf16 ----
// Same structure: A bf16 + B fp32 via global_load_lds, 3-buffer counted vmcnt.
__global__ __launch_bounds__(256, 3) void k_gemm2(const unsigned short* __restrict__ act,
                                                  const float* __restrict__ dwn,
                                                  const int* __restrict__ counts,
                                                  unsigned short* __restrict__ yd) {
  // per buffer: A bf16 4096 | B fp32 4096 ushorts = 16KB -> 3x = 48KB
  __shared__ unsigned short lds[3 * 8192];

  const int bid = blockIdx.x;           // 1024 blocks
  const int xcd = bid & 7, slot = bid >> 3;       // slot 0..127
  const int e = xcd * 4 + (slot >> 5);            // 4 experts per XCD
  const int sub = slot & 31;                      // 32 blocks per expert
  const int c0 = (sub & 7) * 64;                  // 8 col tiles over H
  const int rt = sub >> 3;                        // 4 row tiles
  const int r0 = e * CAP + rt * 128;
  if (rt * 128 >= min(counts[e], CAP)) return;

  const int tid = threadIdx.x;
  const int lane = tid & 63;
  const int wid = tid >> 6;
  const int wr = wid >> 1, wc = wid & 1;
  const int ml = lane & 15, kg = lane >> 4;

  const int rowA = tid & 127, kcA = tid >> 7;
  const unsigned short* a_src = act + (size_t)(r0 + rowA) * I_DIM + kcA * 8;
  const int dA0 = (wid * 64) * 8;
  const int dA1 = (256 + wid * 64) * 8;

  const int nB0 = tid >> 3, kcsB = tid & 7;
  const int kcB0 = kcsB ^ (nB0 & 7);
  const float* b_row0 = dwn + (size_t)e * (H_DIM * I_DIM) + (size_t)(c0 + nB0) * I_DIM + kcB0 * 4;
  const float* b_row1 = b_row0 + (size_t)32 * I_DIM;
  const int dB0 = 4096 + (wid * 64) * 8;
  const int dB1 = 4096 + (256 + wid * 64) * 8;

  float4v acc[4][2] = {};

  auto STAGE = [&](unsigned short* lb, int kk) {
    GLOAD_LDS16(a_src + kk, lb + dA0);
    GLOAD_LDS16(a_src + kk + 16, lb + dA1);
    GLOAD_LDS16(b_row0 + kk, lb + dB0);
    GLOAD_LDS16(b_row1 + kk, lb + dB1);
  };
  auto COMPUTE = [&](const unsigned short* lb) {
    short8 af[4];
#pragma unroll
    for (int mi = 0; mi < 4; ++mi)
      af[mi] = *(const short8*)(lb + (kg * 128 + wr * 64 + mi * 16 + ml) * 8);
    frag_u bf[2];
#pragma unroll
    for (int ni = 0; ni < 2; ++ni) {
      const int n = wc * 32 + ni * 16 + ml;
      const int i0 = (n * 8 + ((2 * kg) ^ (n & 7))) * 8;
      const int i1 = (n * 8 + ((2 * kg + 1) ^ (n & 7))) * 8;
      float4v f0 = *(const float4v*)(lb + 4096 + i0);
      float4v f1 = *(const float4v*)(lb + 4096 + i1);
      bf[ni].u.x = cvtpk(f0.x, f0.y); bf[ni].u.y = cvtpk(f0.z, f0.w);
      bf[ni].u.z = cvtpk(f1.x, f1.y); bf[ni].u.w = cvtpk(f1.z, f1.w);
    }
#pragma unroll
    for (int mi = 0; mi < 4; ++mi)
#pragma unroll
      for (int ni = 0; ni < 2; ++ni)
        acc[mi][ni] = __builtin_amdgcn_mfma_f32_16x16x32_bf16(af[mi], bf[ni].s, acc[mi][ni], 0, 0, 0);
  };

  unsigned short* b0 = lds;
  unsigned short* b1 = lds + 8192;
  unsigned short* b2 = lds + 16384;
  STAGE(b0, 0);
  STAGE(b1, 32);
#pragma unroll 1
  for (int t = 0; t < 30; ++t) {           // NT = I/32 = 32; main body t=0..29
    asm volatile("s_waitcnt vmcnt(4)" ::: "memory");
    __builtin_amdgcn_s_barrier();
    __builtin_amdgcn_sched_barrier(0);
    STAGE(b2, (t + 2) * 32);
    COMPUTE(b0);
    unsigned short* tmp = b0; b0 = b1; b1 = b2; b2 = tmp;
  }
  asm volatile("s_waitcnt vmcnt(4)" ::: "memory");    // t = 30
  __builtin_amdgcn_s_barrier();
  __builtin_amdgcn_sched_barrier(0);
  COMPUTE(b0);
  asm volatile("s_waitcnt vmcnt(0)" ::: "memory");    // t = 31
  __builtin_amdgcn_s_barrier();
  __builtin_amdgcn_sched_barrier(0);
  COMPUTE(b1);

#pragma unroll
  for (int mi = 0; mi < 4; ++mi) {
    const int row = r0 + wr * 64 + mi * 16 + kg * 4;
#pragma unroll
    for (int ni = 0; ni < 2; ++ni) {
      const int col = c0 + wc * 32 + ni * 16 + ml;
#pragma unroll
      for (int rj = 0; rj < 4; ++rj)
        yd[(size_t)(row + rj) * H_DIM + col] = f2bf_rne(acc[mi][ni][rj]);
    }
  }
}

// ---------------- combine: out[t] = sum_k w[t,k] * yd[inv[t,k]] ----------------
__global__ void k_combine(const unsigned short* __restrict__ yd, const int* __restrict__ inv,
                          const float* __restrict__ wts, float* __restrict__ out) {
  const int t = blockIdx.x * 4 + (threadIdx.x >> 6);  // one wave per token
  const int lane = threadIdx.x & 63;
  const int i0 = 2 * t, i1 = 2 * t + 1;
  const int r0 = inv[i0], r1 = inv[i1];
  float o[8] = {0.f, 0.f, 0.f, 0.f, 0.f, 0.f, 0.f, 0.f};
  if (r0 >= 0) {
    float w = wts[i0];
    short8 y = *(const short8*)(yd + (size_t)r0 * H_DIM + lane * 8);
#pragma unroll
    for (int j = 0; j < 8; ++j) o[j] += w * bf2f((unsigned short)y[j]);
  }
  if (r1 >= 0) {
    float w = wts[i1];
    short8 y = *(const short8*)(yd + (size_t)r1 * H_DIM + lane * 8);
#pragma unroll
    for (int j = 0; j < 8; ++j) o[j] += w * bf2f((unsigned short)y[j]);
  }
  float4v v0 = {o[0], o[1], o[2], o[3]};
  float4v v1 = {o[4], o[5], o[6], o[7]};
  float4v* dst = (float4v*)(out + (size_t)t * H_DIM + lane * 8);
  dst[0] = v0;
  dst[1] = v1;
}

extern "C" void kernel_launch(void* const* d_in, const int* in_sizes, int n_in,
                              void* d_out, int out_size, void* d_ws, size_t ws_size,
                              hipStream_t stream) {
  const float* hs  = (const float*)d_in[0];  // [T,H]
  const int*   idx = (const int*)d_in[1];    // [T,K]
  const float* wts = (const float*)d_in[2];  // [T,K]
  const float* gup = (const float*)d_in[3];  // [E,2I,H]
  const float* dwn = (const float*)d_in[4];  // [E,H,I]
  float* out = (float*)d_out;                // [T,H]

  char* ws = (char*)d_ws;
  int* counts       = (int*)ws;                             // 128 B used
  int* inv          = (int*)(ws + 1024);                    // 32 KB
  int* slot_token   = (int*)(ws + 1024 + 32768);            // 64 KB
  unsigned short* xd  = (unsigned short*)(ws + 131072);     // 16.8 MB
  unsigned short* act = xd + (size_t)NROWS * H_DIM;         // 33.6 MB
  unsigned short* yd  = xd;  // xd is dead after gemm1; alias

  hipMemsetAsync(counts, 0, E_NUM * sizeof(int), stream);
  k_route<<<NPAIR / 256, 256, 0, stream>>>(idx, counts, slot_token, inv);
  k_gather<<<NROWS / 4, 256, 0, stream>>>(hs, counts, slot_token, xd);
  k_gemm1<<<2048, 256, 0, stream>>>(xd, gup, counts, act);   // 1D grid, XCD-affine
  k_gemm2<<<1024, 256, 0, stream>>>(act, dwn, counts, yd);
  k_combine<<<T_TOK / 4, 256, 0, stream>>>(yd, inv, wts, out);
}